// Round 7
// baseline (608.871 us; speedup 1.0000x reference)
//
#include <hip/hip_runtime.h>
#include <hip/hip_cooperative_groups.h>
#include <math.h>

namespace cg = cooperative_groups;

#define NLOC 1600
#define NGLO 100

typedef unsigned short u16;
typedef short s16x8 __attribute__((ext_vector_type(8)));   // 8 bf16 (4 VGPRs)
typedef float f32x4 __attribute__((ext_vector_type(4)));   // MFMA C/D

__device__ __forceinline__ short f2bf(float f) {           // RNE f32->bf16
    unsigned u = __float_as_uint(f);
    u += 0x7fffu + ((u >> 16) & 1u);
    return (short)(u >> 16);
}
__device__ __forceinline__ float bf2f(u16 h) {
    return __uint_as_float(((unsigned)h) << 16);
}

struct P {
    const float *x, *gat_W, *gat_b, *cross_W, *cross_b, *ln_g, *ln_b;
    float *out;
    float *nodes, *gn, *gout, *lout, *sv1l, *sv1g, *pO, *pT;
    u16 *wgatb, *wcrsb, *nodesb, *gnb, *qbuf, *kbuf, *vtb, *gqb, *gkb, *gvt,
        *gattb, *goutb, *attb, *loutb, *ckb, *cvt, *cqb, *cattb;
};

// ---------------------------------------------------------------------------
// GEMM core: acc = A[m0..+32, :256] @ W[n0..+64, :256]^T  (both bf16)
// ---------------------------------------------------------------------------
__device__ __forceinline__ void gemm_core(int lane, const u16* __restrict__ A,
                                          const u16* __restrict__ W,
                                          int M, int m0, int n0, f32x4 acc[2][4]) {
    int c = lane & 15, qd = lane >> 4;
#pragma unroll
    for (int mi = 0; mi < 2; ++mi)
#pragma unroll
        for (int ni = 0; ni < 4; ++ni) acc[mi][ni] = (f32x4){0.f, 0.f, 0.f, 0.f};
#pragma unroll 2
    for (int kc = 0; kc < 8; ++kc) {
        int ko = kc * 32 + qd * 8;
        s16x8 af[2], bf[4];
#pragma unroll
        for (int mi = 0; mi < 2; ++mi) {
            int row = m0 + mi * 16 + c;
            s16x8 zz = {};
            af[mi] = (row < M) ? *(const s16x8*)(A + (size_t)row * 256 + ko) : zz;
        }
#pragma unroll
        for (int ni = 0; ni < 4; ++ni)
            bf[ni] = *(const s16x8*)(W + (size_t)(n0 + ni * 16 + c) * 256 + ko);
#pragma unroll
        for (int mi = 0; mi < 2; ++mi)
#pragma unroll
            for (int ni = 0; ni < 4; ++ni)
                acc[mi][ni] = __builtin_amdgcn_mfma_f32_16x16x32_bf16(af[mi], bf[ni],
                                                                      acc[mi][ni], 0, 0, 0);
    }
}

// Row-major bf16 epilogue
__device__ __forceinline__ void ep_row(int lane, f32x4 acc[2][4],
                                       const float* __restrict__ bias,
                                       u16* __restrict__ C, int M, int m0, int n0) {
    int c = lane & 15, qd = lane >> 4;
#pragma unroll
    for (int mi = 0; mi < 2; ++mi)
#pragma unroll
        for (int r = 0; r < 4; ++r) {
            int row = m0 + mi * 16 + 4 * qd + r;
            if (row < M) {
#pragma unroll
                for (int ni = 0; ni < 4; ++ni) {
                    int col = n0 + ni * 16 + c;
                    C[(size_t)row * 256 + col] = (u16)f2bf(acc[mi][ni][r] + bias[col]);
                }
            }
        }
}

// Transposed V epilogue: vt[b][col][n] (+ optional batch-1 colsum atomics)
__device__ __forceinline__ void ep_vt(int lane, f32x4 acc[2][4],
                                      const float* __restrict__ bias,
                                      u16* __restrict__ vt, int Npad,
                                      int M, int m0, int n0, float* sum) {
    int c = lane & 15, qd = lane >> 4;
    float s[4] = {0.f, 0.f, 0.f, 0.f};
#pragma unroll
    for (int mi = 0; mi < 2; ++mi)
#pragma unroll
        for (int r = 0; r < 4; ++r) {
            int row = m0 + mi * 16 + 4 * qd + r;
            if (row < M) {
                int n = row >> 1, b = row & 1;
#pragma unroll
                for (int ni = 0; ni < 4; ++ni) {
                    int col = n0 + ni * 16 + c;
                    float val = acc[mi][ni][r] + bias[col];
                    vt[(size_t)(b * 256 + col) * Npad + n] = (u16)f2bf(val);
                    if (b) s[ni] += val;
                }
            }
        }
    if (sum) {
#pragma unroll
        for (int ni = 0; ni < 4; ++ni)
            atomicAdd(&sum[n0 + ni * 16 + c], s[ni]);
    }
}

// Fused GEMM + LayerNorm, whole block: 16 rows x 256 cols.
// MODE 0: fout f32 + bfout bf16. MODE 1: BCHW write via LDS staging.
template <int MODE>
__device__ __forceinline__ void gemmln_block(int tid, unsigned char* smem,
                                             const u16* __restrict__ A,
                                             const u16* __restrict__ W,
                                             const float* __restrict__ bias,
                                             const float* __restrict__ R,
                                             const float* __restrict__ g,
                                             const float* __restrict__ bb,
                                             float* fout, u16* bfout, float* dout,
                                             int M, int m0) {
    int w = tid >> 6, lane = tid & 63;
    int c = lane & 15, qd = lane >> 4;
    int n0 = w * 64;
    float (*ps1)[16] = (float(*)[16])smem;            // 256 B
    float (*ps2)[16] = (float(*)[16])(smem + 256);    // 256 B
    float (*ytile)[8][256] = (float(*)[8][256])(smem + 512);   // 16 KB (MODE1)

    f32x4 acc[4] = {};
#pragma unroll 2
    for (int kc = 0; kc < 8; ++kc) {
        int ko = kc * 32 + qd * 8;
        int row = m0 + c;
        s16x8 zz = {};
        s16x8 af = (row < M) ? *(const s16x8*)(A + (size_t)row * 256 + ko) : zz;
#pragma unroll
        for (int ni = 0; ni < 4; ++ni) {
            s16x8 bf = *(const s16x8*)(W + (size_t)(n0 + ni * 16 + c) * 256 + ko);
            acc[ni] = __builtin_amdgcn_mfma_f32_16x16x32_bf16(af, bf, acc[ni], 0, 0, 0);
        }
    }

    float v[4][4];
#pragma unroll
    for (int r = 0; r < 4; ++r) {
        int row = m0 + 4 * qd + r;
        bool ok = (row < M);
        float s1 = 0.f, s2 = 0.f;
#pragma unroll
        for (int ni = 0; ni < 4; ++ni) {
            int col = n0 + ni * 16 + c;
            float val = acc[ni][r] + bias[col] + (ok ? R[(size_t)row * 256 + col] : 0.f);
            v[r][ni] = val;
            s1 += val; s2 += val * val;
        }
        s1 += __shfl_xor(s1, 1); s2 += __shfl_xor(s2, 1);
        s1 += __shfl_xor(s1, 2); s2 += __shfl_xor(s2, 2);
        s1 += __shfl_xor(s1, 4); s2 += __shfl_xor(s2, 4);
        s1 += __shfl_xor(s1, 8); s2 += __shfl_xor(s2, 8);
        if (c == 0) { ps1[w][4 * qd + r] = s1; ps2[w][4 * qd + r] = s2; }
    }
    __syncthreads();

    if (MODE == 0) {
#pragma unroll
        for (int r = 0; r < 4; ++r) {
            int lr = 4 * qd + r;
            int row = m0 + lr;
            if (row >= M) continue;
            float s1 = ps1[0][lr] + ps1[1][lr] + ps1[2][lr] + ps1[3][lr];
            float s2 = ps2[0][lr] + ps2[1][lr] + ps2[2][lr] + ps2[3][lr];
            float mean = s1 * (1.f / 256.f);
            float var  = s2 * (1.f / 256.f) - mean * mean;
            float rstd = rsqrtf(var + 1e-5f);
#pragma unroll
            for (int ni = 0; ni < 4; ++ni) {
                int col = n0 + ni * 16 + c;
                float y = (v[r][ni] - mean) * rstd * g[col] + bb[col];
                fout[(size_t)row * 256 + col] = y;
                bfout[(size_t)row * 256 + col] = (u16)f2bf(y);
            }
        }
    } else {
#pragma unroll
        for (int r = 0; r < 4; ++r) {
            int lr = 4 * qd + r;
            float s1 = ps1[0][lr] + ps1[1][lr] + ps1[2][lr] + ps1[3][lr];
            float s2 = ps2[0][lr] + ps2[1][lr] + ps2[2][lr] + ps2[3][lr];
            float mean = s1 * (1.f / 256.f);
            float var  = s2 * (1.f / 256.f) - mean * mean;
            float rstd = rsqrtf(var + 1e-5f);
#pragma unroll
            for (int ni = 0; ni < 4; ++ni) {
                int col = n0 + ni * 16 + c;
                ytile[lr & 1][lr >> 1][col] = (v[r][ni] - mean) * rstd * g[col] + bb[col];
            }
        }
        __syncthreads();
#pragma unroll
        for (int pp = tid; pp < 512; pp += 256) {
            int b = pp >> 8, col = pp & 255;
            float4 y0, y1;
            y0.x = ytile[b][0][col]; y0.y = ytile[b][1][col];
            y0.z = ytile[b][2][col]; y0.w = ytile[b][3][col];
            y1.x = ytile[b][4][col]; y1.y = ytile[b][5][col];
            y1.z = ytile[b][6][col]; y1.w = ytile[b][7][col];
            size_t o = ((size_t)(b * 256 + col)) * 1600 + (m0 >> 1);
            *(float4*)(dout + o)     = y0;
            *(float4*)(dout + o + 4) = y1;
        }
    }
    __syncthreads();   // protect smem reuse across task-loop iterations
}

// ===========================================================================
// The mega-kernel: 8 stages, 7 grid syncs, persistent co-resident grid.
// ===========================================================================
__global__ __launch_bounds__(256, 4) void mega(P p) {
    cg::grid_group grid = cg::this_grid();
    __shared__ __align__(16) unsigned char smem[17536];
    const int tid = threadIdx.x;
    const int w = tid >> 6, lane = tid & 63;
    const int c = lane & 15, qd = lane >> 4;
    const int nB = gridDim.x;

    // ---------------- Stage 1: wconv + x transpose + pool + zero-init ------
    for (int task = blockIdx.x; task < 1771; task += nB) {
        if (task < 768) {
            int t = task * 256 + tid;
            const float* src; u16* dst; int idx;
            if (t < 131072) { src = p.gat_W; dst = p.wgatb; idx = t; }
            else            { src = p.cross_W; dst = p.wcrsb; idx = t - 131072; }
            float4 v = ((const float4*)src)[idx];
            ushort4 o;
            o.x = (u16)f2bf(v.x); o.y = (u16)f2bf(v.y);
            o.z = (u16)f2bf(v.z); o.w = (u16)f2bf(v.w);
            ((ushort4*)dst)[idx] = o;
        } else if (task < 1568) {
            // LDS-tiled transpose: x[b][c][n] -> nodes[n][b][c] (f32+bf16)
            float (*tile)[33] = (float(*)[33])smem;
            int tt = task - 768;
            int cb = tt / 100, rem = tt - cb * 100;
            int nb = rem >> 1, b = rem & 1;
            int c0 = cb * 32, n0t = nb * 32;
            int tx = tid & 31, ty = tid >> 5;
#pragma unroll
            for (int k2 = 0; k2 < 4; ++k2) {
                int cc = c0 + ty + k2 * 8;
                tile[ty + k2 * 8][tx] = p.x[((size_t)(b * 256 + cc)) * 1600 + n0t + tx];
            }
            __syncthreads();
#pragma unroll
            for (int k2 = 0; k2 < 4; ++k2) {
                int n = n0t + ty + k2 * 8;
                float val = tile[tx][ty + k2 * 8];
                size_t o = ((size_t)(n * 2 + b)) * 256 + c0 + tx;
                p.nodes[o] = val;
                p.nodesb[o] = (u16)f2bf(val);
            }
            __syncthreads();
        } else if (task < 1768) {
            int pt = task - 1568;          // 0..199
            int b = pt & 1, n = pt >> 1;
            int cc = tid;
            int pr = n / 10, qqc = n - pr * 10;
            const float* xp = p.x + ((size_t)(b * 256 + cc)) * 1600 + (pr * 4) * 40 + qqc * 4;
            float s = 0.f;
#pragma unroll
            for (int dy = 0; dy < 4; ++dy)
#pragma unroll
                for (int dx = 0; dx < 4; ++dx)
                    s += xp[dy * 40 + dx];
            s *= (1.f / 16.f);
            size_t t = (size_t)pt * 256 + cc;
            p.gn[t] = s;
            p.gnb[t] = (u16)f2bf(s);
        } else if (task == 1768) {
            p.sv1l[tid] = 0.f;             // sv1l[0..255] + sv1g[0..255] contiguous
            p.sv1l[tid + 256] = 0.f;
        } else if (task == 1769) {
            for (int e2 = tid; e2 < 512; e2 += 256)
                for (int n = 100; n < 128; ++n) p.gvt[(size_t)e2 * 128 + n] = 0;
        } else {   // 1770
            for (int e2 = tid; e2 < 512; e2 += 256)
                for (int n = 100; n < 128; ++n) p.cvt[(size_t)e2 * 128 + n] = 0;
        }
    }
    grid.sync();

    // ---------------- Stage 2: QKV GEMMs (V written transposed + colsum) ---
    for (int wt = blockIdx.x * 4 + w; wt < 1284; wt += nB * 4) {
        int z = wt / 428, rem = wt - z * 428;
        int y = rem / 107, bx = rem - y * 107;
        int n0 = y * 64;
        f32x4 acc[2][4];
        if (bx < 100) {
            int m0 = bx * 32;
            gemm_core(lane, p.nodesb, p.wgatb + (size_t)(4 + z) * 65536, 3200, m0, n0, acc);
            const float* bias = p.gat_b + (4 + z) * 256;
            if (z == 0)      ep_row(lane, acc, bias, p.qbuf, 3200, m0, n0);
            else if (z == 1) ep_row(lane, acc, bias, p.kbuf, 3200, m0, n0);
            else             ep_vt(lane, acc, bias, p.vtb, 1600, 3200, m0, n0, p.sv1l);
        } else {
            int m0 = (bx - 100) * 32;
            gemm_core(lane, p.gnb, p.wgatb + (size_t)z * 65536, 200, m0, n0, acc);
            const float* bias = p.gat_b + z * 256;
            if (z == 0)      ep_row(lane, acc, bias, p.gqb, 200, m0, n0);
            else if (z == 1) ep_row(lane, acc, bias, p.gkb, 200, m0, n0);
            else             ep_vt(lane, acc, bias, p.gvt, 128, 200, m0, n0, p.sv1g);
        }
    }
    grid.sync();

    // ---------------- Stage 3: attention (local + global GAT) --------------
    {
        u16 (*ks)[32][40] = (u16(*)[32][40])smem;
        u16 (*vs)[32][40] = (u16(*)[32][40])(smem + 5120);
        short (*At4)[16][40] = (short(*)[16][40])(smem + 10240);
        for (int task = blockIdx.x; task < 814; task += nB) {
            if (task < 800) {
                int q4 = task & 3;
                int hic = task >> 2;
                int ic = hic % 25, h = hic / 25;
                int hb = h * 32;
                int i0 = ic * 64 + w * 16;
                int jb0 = q4 * 13, jbe = (jb0 + 13 < 50) ? jb0 + 13 : 50;

                const u16* qp = p.qbuf + ((size_t)(i0 + c) * 2) * 256 + hb + qd * 8;
                s16x8 qf0 = *(const s16x8*)qp;
                s16x8 qf1 = *(const s16x8*)(qp + 256);
#pragma unroll
                for (int z = 0; z < 8; ++z) qf0[z] ^= (short)0x8000;

                f32x4 o0[2] = {}, t1[2] = {};
                int srow = tid >> 2, part = tid & 3;
                int sjl = srow >> 1, sb = srow & 1;
                int vb_ = srow >> 5, vd = srow & 31;

                for (int jb = jb0; jb < jbe; ++jb) {
                    int j0 = jb * 32;
                    __syncthreads();
                    {
                        s16x8 kv = *(const s16x8*)(p.kbuf + (size_t)(j0 + sjl) * 512 + sb * 256 + hb + part * 8);
                        *(s16x8*)&ks[sb][sjl][part * 8] = kv;
                        s16x8 vv = *(const s16x8*)(p.vtb + (size_t)(vb_ * 256 + hb + vd) * 1600 + j0 + part * 8);
                        *(s16x8*)&vs[vb_][vd][part * 8] = vv;
                    }
                    __syncthreads();

                    s16x8 kf00 = *(const s16x8*)&ks[0][c][qd * 8];
                    s16x8 kf10 = *(const s16x8*)&ks[1][c][qd * 8];
                    s16x8 kf01 = *(const s16x8*)&ks[0][16 + c][qd * 8];
                    s16x8 kf11 = *(const s16x8*)&ks[1][16 + c][qd * 8];

                    f32x4 z4 = {};
                    f32x4 sd0 = __builtin_amdgcn_mfma_f32_16x16x32_bf16(qf0, kf00, z4, 0, 0, 0);
                    sd0       = __builtin_amdgcn_mfma_f32_16x16x32_bf16(qf1, kf10, sd0, 0, 0, 0);
                    f32x4 sd1 = __builtin_amdgcn_mfma_f32_16x16x32_bf16(qf0, kf01, z4, 0, 0, 0);
                    sd1       = __builtin_amdgcn_mfma_f32_16x16x32_bf16(qf1, kf11, sd1, 0, 0, 0);
#pragma unroll
                    for (int r = 0; r < 4; ++r) {
                        float e0v = __expf(sd0[r] * 0.17677669529663687f);
                        At4[w][4 * qd + r][c]      = f2bf(__builtin_amdgcn_rcpf(1.f + e0v));
                        float e1v = __expf(sd1[r] * 0.17677669529663687f);
                        At4[w][4 * qd + r][16 + c] = f2bf(__builtin_amdgcn_rcpf(1.f + e1v));
                    }
                    asm volatile("s_waitcnt lgkmcnt(0)" ::: "memory");
                    s16x8 af = *(const s16x8*)&At4[w][c][qd * 8];

                    s16x8 vf00 = *(const s16x8*)&vs[0][c][qd * 8];
                    s16x8 vf01 = *(const s16x8*)&vs[0][16 + c][qd * 8];
                    s16x8 vf10 = *(const s16x8*)&vs[1][c][qd * 8];
                    s16x8 vf11 = *(const s16x8*)&vs[1][16 + c][qd * 8];

                    o0[0] = __builtin_amdgcn_mfma_f32_16x16x32_bf16(af, vf00, o0[0], 0, 0, 0);
                    o0[1] = __builtin_amdgcn_mfma_f32_16x16x32_bf16(af, vf01, o0[1], 0, 0, 0);
                    t1[0] = __builtin_amdgcn_mfma_f32_16x16x32_bf16(af, vf10, t1[0], 0, 0, 0);
                    t1[1] = __builtin_amdgcn_mfma_f32_16x16x32_bf16(af, vf11, t1[1], 0, 0, 0);
                }

                size_t base = (size_t)q4 * 409600;
#pragma unroll
                for (int dh = 0; dh < 2; ++dh)
#pragma unroll
                    for (int r = 0; r < 4; ++r) {
                        size_t idx = base + (size_t)(i0 + 4 * qd + r) * 256 + hb + dh * 16 + c;
                        p.pO[idx] = o0[dh][r];
                        p.pT[idx] = t1[dh][r];
                    }
                __syncthreads();
            } else {
                int idx = (task - 800) * 4 + w;      // 0..55
                int h = idx / 7, it = idx % 7;
                int i0 = it * 16;
                int hb = h * 32;

                s16x8 qf0 = {}, qf1 = {};
                int i = i0 + c;
                if (i < NGLO) {
                    const u16* qp = p.gqb + ((size_t)i * 2) * 256 + hb + qd * 8;
                    qf0 = *(const s16x8*)qp;
                    qf1 = *(const s16x8*)(qp + 256);
                }
#pragma unroll
                for (int z = 0; z < 8; ++z) qf0[z] ^= (short)0x8000;

                f32x4 o0[2] = {}, t1[2] = {};
                for (int j0 = 0; j0 < NGLO; j0 += 32) {
                    s16x8 kf[2][2], vf[2][2];
#pragma unroll
                    for (int b = 0; b < 2; ++b)
#pragma unroll
                        for (int js = 0; js < 2; ++js) {
                            int j = j0 + js * 16 + c;
                            s16x8 kv = {};
                            if (j < NGLO) kv = *(const s16x8*)(p.gkb + ((size_t)j * 2 + b) * 256 + hb + qd * 8);
                            kf[b][js] = kv;
                        }
#pragma unroll
                    for (int b = 0; b < 2; ++b)
#pragma unroll
                        for (int dh = 0; dh < 2; ++dh)
                            vf[b][dh] = *(const s16x8*)(p.gvt + (size_t)(b * 256 + hb + dh * 16 + c) * 128
                                                        + j0 + qd * 8);

                    f32x4 z4 = {};
                    f32x4 sd0 = __builtin_amdgcn_mfma_f32_16x16x32_bf16(qf0, kf[0][0], z4, 0, 0, 0);
                    sd0       = __builtin_amdgcn_mfma_f32_16x16x32_bf16(qf1, kf[1][0], sd0, 0, 0, 0);
                    f32x4 sd1 = __builtin_amdgcn_mfma_f32_16x16x32_bf16(qf0, kf[0][1], z4, 0, 0, 0);
                    sd1       = __builtin_amdgcn_mfma_f32_16x16x32_bf16(qf1, kf[1][1], sd1, 0, 0, 0);
#pragma unroll
                    for (int r = 0; r < 4; ++r) {
                        float e0v = __expf(sd0[r] * 0.17677669529663687f);
                        At4[w][4 * qd + r][c]      = f2bf(__builtin_amdgcn_rcpf(1.f + e0v));
                        float e1v = __expf(sd1[r] * 0.17677669529663687f);
                        At4[w][4 * qd + r][16 + c] = f2bf(__builtin_amdgcn_rcpf(1.f + e1v));
                    }
                    asm volatile("s_waitcnt lgkmcnt(0)" ::: "memory");
                    s16x8 af = *(const s16x8*)&At4[w][c][qd * 8];
                    o0[0] = __builtin_amdgcn_mfma_f32_16x16x32_bf16(af, vf[0][0], o0[0], 0, 0, 0);
                    o0[1] = __builtin_amdgcn_mfma_f32_16x16x32_bf16(af, vf[0][1], o0[1], 0, 0, 0);
                    t1[0] = __builtin_amdgcn_mfma_f32_16x16x32_bf16(af, vf[1][0], t1[0], 0, 0, 0);
                    t1[1] = __builtin_amdgcn_mfma_f32_16x16x32_bf16(af, vf[1][1], t1[1], 0, 0, 0);
                }
#pragma unroll
                for (int dh = 0; dh < 2; ++dh) {
                    float sv = p.sv1g[hb + dh * 16 + c];
#pragma unroll
                    for (int r = 0; r < 4; ++r) {
                        int ii = i0 + 4 * qd + r;
                        if (ii < NGLO) {
                            size_t o = ((size_t)ii * 2) * 256 + hb + dh * 16 + c;
                            p.gattb[o]       = (u16)f2bf(o0[dh][r]);
                            p.gattb[o + 256] = (u16)f2bf(sv - t1[dh][r]);
                        }
                    }
                }
                __syncthreads();
            }
        }
    }
    grid.sync();

    // ---------------- Stage 4: combine + global proj+LN --------------------
    for (int task = blockIdx.x; task < 413; task += nB) {
        if (task < 400) {
            int t4 = (task * 256 + tid) * 4;
            int e = t4 & 255;
            int i = t4 >> 8;
            float4 o  = *(const float4*)(p.pO + t4);
            float4 tt = *(const float4*)(p.pT + t4);
#pragma unroll
            for (int q = 1; q < 4; ++q) {
                float4 a = *(const float4*)(p.pO + t4 + q * 409600);
                float4 b = *(const float4*)(p.pT + t4 + q * 409600);
                o.x += a.x; o.y += a.y; o.z += a.z; o.w += a.w;
                tt.x += b.x; tt.y += b.y; tt.z += b.z; tt.w += b.w;
            }
            float4 sv = *(const float4*)(p.sv1l + e);
            ushort4 w0, w1;
            w0.x = (u16)f2bf(o.x); w0.y = (u16)f2bf(o.y);
            w0.z = (u16)f2bf(o.z); w0.w = (u16)f2bf(o.w);
            w1.x = (u16)f2bf(sv.x - tt.x); w1.y = (u16)f2bf(sv.y - tt.y);
            w1.z = (u16)f2bf(sv.z - tt.z); w1.w = (u16)f2bf(sv.w - tt.w);
            *(ushort4*)(p.attb + (size_t)i * 512 + e)       = w0;
            *(ushort4*)(p.attb + (size_t)i * 512 + 256 + e) = w1;
        } else {
            gemmln_block<0>(tid, smem, p.gattb, p.wgatb + 3 * 65536, p.gat_b + 768,
                            p.gn, p.ln_g, p.ln_b, p.gout, p.goutb, (float*)0,
                            200, (task - 400) * 16);
        }
    }
    grid.sync();

    // ---------------- Stage 5: local proj+LN + ck/cv GEMM ------------------
    for (int task = blockIdx.x; task < 214; task += nB) {
        if (task < 200) {
            gemmln_block<0>(tid, smem, p.attb, p.wgatb + 7 * 65536, p.gat_b + 1792,
                            p.nodes, p.ln_g + 256, p.ln_b + 256, p.lout, p.loutb,
                            (float*)0, 3200, task * 16);
        } else {
            int idx = (task - 200) * 4 + w;                  // 0..55
            if (idx < 56) {
                int z = idx / 28, rem = idx % 28;
                int m0 = (rem >> 2) * 32, n0 = (rem & 3) * 64;
                f32x4 acc[2][4];
                gemm_core(lane, p.goutb, p.wcrsb + (size_t)(1 + z) * 65536, 200, m0, n0, acc);
                const float* bias = p.cross_b + (1 + z) * 256;
                if (z == 0) ep_row(lane, acc, bias, p.ckb, 200, m0, n0);
                else        ep_vt(lane, acc, bias, p.cvt, 128, 200, m0, n0, (float*)0);
            }
        }
    }
    grid.sync();

    // ---------------- Stage 6: cq GEMM -------------------------------------
    for (int wt = blockIdx.x * 4 + w; wt < 400; wt += nB * 4) {
        int m0 = (wt % 100) * 32, n0 = (wt / 100) * 64;
        f32x4 acc[2][4];
        gemm_core(lane, p.loutb, p.wcrsb, 3200, m0, n0, acc);
        ep_row(lane, acc, p.cross_b, p.cqb, 3200, m0, n0);
    }
    grid.sync();

    // ---------------- Stage 7: cross attention -----------------------------
    {
        short (*Atc)[16][136] = (short(*)[16][136])smem;
        for (int task = blockIdx.x; task < 400; task += nB) {
            int idx = task * 4 + w;
            int it = idx % 100;
            int hb2 = idx / 100;
            int h = hb2 >> 1, b = hb2 & 1;
            int i0 = it * 16;
            int hb = h * 32;

            for (int z = lane; z < 16 * 24; z += 64)
                Atc[w][z / 24][112 + (z % 24)] = 0;

            const u16* qp = p.cqb + ((size_t)(i0 + c) * 2 + b) * 256 + hb + qd * 8;
            s16x8 qf = *(const s16x8*)qp;

            f32x4 s[7];
#pragma unroll
            for (int jt = 0; jt < 7; ++jt) {
                int j = jt * 16 + c;
                s16x8 kf = {};
                if (j < NGLO) kf = *(const s16x8*)(p.ckb + ((size_t)j * 2 + b) * 256 + hb + qd * 8);
                f32x4 z4 = {};
                s[jt] = __builtin_amdgcn_mfma_f32_16x16x32_bf16(qf, kf, z4, 0, 0, 0);
            }
            if (c >= 4) {
#pragma unroll
                for (int r = 0; r < 4; ++r) s[6][r] = -1e30f;
            }
#pragma unroll
            for (int jt = 0; jt < 7; ++jt)
#pragma unroll
                for (int r = 0; r < 4; ++r) s[jt][r] *= 0.17677669529663687f;

            float l[4];
#pragma unroll
            for (int r = 0; r < 4; ++r) {
                float mm = s[0][r];
#pragma unroll
                for (int jt = 1; jt < 7; ++jt) mm = fmaxf(mm, s[jt][r]);
                mm = fmaxf(mm, __shfl_xor(mm, 1));
                mm = fmaxf(mm, __shfl_xor(mm, 2));
                mm = fmaxf(mm, __shfl_xor(mm, 4));
                mm = fmaxf(mm, __shfl_xor(mm, 8));
                float ll = 0.f;
#pragma unroll
                for (int jt = 0; jt < 7; ++jt) {
                    float pv = __expf(s[jt][r] - mm);
                    s[jt][r] = pv;
                    ll += pv;
                }
                ll += __shfl_xor(ll, 1);
                ll += __shfl_xor(ll, 2);
                ll += __shfl_xor(ll, 4);
                ll += __shfl_xor(ll, 8);
                l[r] = ll;
            }
#pragma unroll
            for (int jt = 0; jt < 7; ++jt)
#pragma unroll
                for (int r = 0; r < 4; ++r)
                    Atc[w][4 * qd + r][jt * 16 + c] = f2bf(s[jt][r]);
            asm volatile("s_waitcnt lgkmcnt(0)" ::: "memory");

            f32x4 o[2] = {};
#pragma unroll
            for (int kc = 0; kc < 4; ++kc) {
                s16x8 af = *(const s16x8*)&Atc[w][c][kc * 32 + qd * 8];
#pragma unroll
                for (int dh = 0; dh < 2; ++dh) {
                    s16x8 vf = *(const s16x8*)(p.cvt + (size_t)(b * 256 + hb + dh * 16 + c) * 128
                                               + kc * 32 + qd * 8);
                    o[dh] = __builtin_amdgcn_mfma_f32_16x16x32_bf16(af, vf, o[dh], 0, 0, 0);
                }
            }
#pragma unroll
            for (int dh = 0; dh < 2; ++dh)
#pragma unroll
                for (int r = 0; r < 4; ++r) {
                    int ii = i0 + 4 * qd + r;
                    p.cattb[((size_t)ii * 2 + b) * 256 + hb + dh * 16 + c] = (u16)f2bf(o[dh][r] / l[r]);
                }
        }
    }
    grid.sync();

    // ---------------- Stage 8: final cproj+LN -> BCHW out ------------------
    for (int task = blockIdx.x; task < 200; task += nB) {
        gemmln_block<1>(tid, smem, p.cattb, p.wcrsb + 3 * 65536, p.cross_b + 768,
                        p.lout, p.ln_g + 512, p.ln_b + 512,
                        (float*)0, (u16*)0, p.out, 3200, task * 16);
    }
}

// ===========================================================================
extern "C" void kernel_launch(void* const* d_in, const int* in_sizes, int n_in,
                              void* d_out, int out_size, void* d_ws, size_t ws_size,
                              hipStream_t stream) {
    float* ws = (float*)d_ws;

    P p;
    p.x       = (const float*)d_in[0];
    p.gat_W   = (const float*)d_in[1];
    p.gat_b   = (const float*)d_in[2];
    // d_in[3] = gat_rel: cancels in the batch-axis softmax -> unused
    p.cross_W = (const float*)d_in[4];
    p.cross_b = (const float*)d_in[5];
    p.ln_g    = (const float*)d_in[6];
    p.ln_b    = (const float*)d_in[7];
    p.out     = (float*)d_out;

    p.nodes = ws;                         // [1600*2][256] f32
    p.gn    = p.nodes + 819200;           // [200][256]
    p.gout  = p.gn + 51200;
    p.lout  = p.gout + 51200;             // [3200][256]
    p.sv1l  = p.lout + 819200;            // [256]; sv1g contiguous after
    p.sv1g  = p.sv1l + 256;
    p.pO    = p.sv1g + 256;               // [4][1600][256]
    p.pT    = p.pO + 1638400;

    u16* ub = (u16*)(p.pT + 1638400);
    p.wgatb  = ub;                 ub += 524288;
    p.wcrsb  = ub;                 ub += 262144;
    p.nodesb = ub;                 ub += 819200;
    p.gnb    = ub;                 ub += 51200;
    p.qbuf   = ub;                 ub += 819200;
    p.kbuf   = ub;                 ub += 819200;
    p.vtb    = ub;                 ub += 819200;
    p.gqb    = ub;                 ub += 51200;
    p.gkb    = ub;                 ub += 51200;
    p.gvt    = ub;                 ub += 65536;
    p.gattb  = ub;                 ub += 51200;
    p.goutb  = ub;                 ub += 51200;
    p.attb   = ub;                 ub += 819200;
    p.loutb  = ub;                 ub += 819200;
    p.ckb    = ub;                 ub += 51200;
    p.cvt    = ub;                 ub += 65536;
    p.cqb    = ub;                 ub += 819200;
    p.cattb  = ub;                 ub += 819200;

    int nbPerCU = 0;
    hipOccupancyMaxActiveBlocksPerMultiprocessor(&nbPerCU, mega, 256, 0);
    if (nbPerCU < 1) nbPerCU = 1;
    int dev = 0;
    hipGetDevice(&dev);
    int ncu = 0;
    hipDeviceGetAttribute(&ncu, hipDeviceAttributeMultiprocessorCount, dev);
    if (ncu < 1) ncu = 256;
    int gridN = nbPerCU * ncu;
    if (gridN > 1024) gridN = 1024;

    void* args[] = {&p};
    hipLaunchCooperativeKernel(mega, dim3(gridN), dim3(256), args, 0, stream);
}

// Round 8
// 185.246 us; speedup vs baseline: 3.2868x; 3.2868x over previous
//
#include <hip/hip_runtime.h>
#include <math.h>

#define NLOC 1600
#define NGLO 100

typedef unsigned short u16;
typedef short s16x8 __attribute__((ext_vector_type(8)));   // 8 bf16 (4 VGPRs)
typedef float f32x4 __attribute__((ext_vector_type(4)));   // MFMA C/D

__device__ __forceinline__ short f2bf(float f) {           // RNE f32->bf16
    unsigned u = __float_as_uint(f);
    u += 0x7fffu + ((u >> 16) & 1u);
    return (short)(u >> 16);
}
__device__ __forceinline__ float bf2f(u16 h) {
    return __uint_as_float(((unsigned)h) << 16);
}

// ---------------------------------------------------------------------------
// GEMM core: acc = A[m0..+32, :256] @ W[n0..+64, :256]^T  (both bf16)
// ---------------------------------------------------------------------------
__device__ __forceinline__ void gemm_core(int lane, const u16* __restrict__ A,
                                          const u16* __restrict__ W,
                                          int M, int m0, int n0, f32x4 acc[2][4]) {
    int c = lane & 15, qd = lane >> 4;
#pragma unroll
    for (int mi = 0; mi < 2; ++mi)
#pragma unroll
        for (int ni = 0; ni < 4; ++ni) acc[mi][ni] = (f32x4){0.f, 0.f, 0.f, 0.f};
#pragma unroll 2
    for (int kc = 0; kc < 8; ++kc) {
        int ko = kc * 32 + qd * 8;
        s16x8 af[2], bf[4];
#pragma unroll
        for (int mi = 0; mi < 2; ++mi) {
            int row = m0 + mi * 16 + c;
            s16x8 zz = {};
            af[mi] = (row < M) ? *(const s16x8*)(A + (size_t)row * 256 + ko) : zz;
        }
#pragma unroll
        for (int ni = 0; ni < 4; ++ni)
            bf[ni] = *(const s16x8*)(W + (size_t)(n0 + ni * 16 + c) * 256 + ko);
#pragma unroll
        for (int mi = 0; mi < 2; ++mi)
#pragma unroll
            for (int ni = 0; ni < 4; ++ni)
                acc[mi][ni] = __builtin_amdgcn_mfma_f32_16x16x32_bf16(af[mi], bf[ni],
                                                                      acc[mi][ni], 0, 0, 0);
    }
}

// Row-major bf16 epilogue
__device__ __forceinline__ void ep_row(int lane, f32x4 acc[2][4],
                                       const float* __restrict__ bias,
                                       u16* __restrict__ C, int M, int m0, int n0) {
    int c = lane & 15, qd = lane >> 4;
#pragma unroll
    for (int mi = 0; mi < 2; ++mi)
#pragma unroll
        for (int r = 0; r < 4; ++r) {
            int row = m0 + mi * 16 + 4 * qd + r;
            if (row < M) {
#pragma unroll
                for (int ni = 0; ni < 4; ++ni) {
                    int col = n0 + ni * 16 + c;
                    C[(size_t)row * 256 + col] = (u16)f2bf(acc[mi][ni][r] + bias[col]);
                }
            }
        }
}

// Transposed V epilogue: vt[b][col][n] (+ optional batch-1 colsum atomics)
// [validated R7]
__device__ __forceinline__ void ep_vt(int lane, f32x4 acc[2][4],
                                      const float* __restrict__ bias,
                                      u16* __restrict__ vt, int Npad,
                                      int M, int m0, int n0, float* sum) {
    int c = lane & 15, qd = lane >> 4;
    float s[4] = {0.f, 0.f, 0.f, 0.f};
#pragma unroll
    for (int mi = 0; mi < 2; ++mi)
#pragma unroll
        for (int r = 0; r < 4; ++r) {
            int row = m0 + mi * 16 + 4 * qd + r;
            if (row < M) {
                int n = row >> 1, b = row & 1;
#pragma unroll
                for (int ni = 0; ni < 4; ++ni) {
                    int col = n0 + ni * 16 + c;
                    float val = acc[mi][ni][r] + bias[col];
                    vt[(size_t)(b * 256 + col) * Npad + n] = (u16)f2bf(val);
                    if (b) s[ni] += val;
                }
            }
        }
    if (sum) {
#pragma unroll
        for (int ni = 0; ni < 4; ++ni)
            atomicAdd(&sum[n0 + ni * 16 + c], s[ni]);
    }
}

// Fused GEMM + LayerNorm, 4-wave block: 16 rows x 256 cols. [validated R6]
template <int MODE>
__device__ __forceinline__ void gemmln_block(int tid, const u16* __restrict__ A,
                                             const u16* __restrict__ W,
                                             const float* __restrict__ bias,
                                             const float* __restrict__ R,
                                             const float* __restrict__ g,
                                             const float* __restrict__ bb,
                                             float* fout, u16* bfout, float* dout,
                                             int M, int m0) {
    int w = tid >> 6, lane = tid & 63;
    int c = lane & 15, qd = lane >> 4;
    int n0 = w * 64;

    f32x4 acc[4] = {};
#pragma unroll 2
    for (int kc = 0; kc < 8; ++kc) {
        int ko = kc * 32 + qd * 8;
        int row = m0 + c;
        s16x8 zz = {};
        s16x8 af = (row < M) ? *(const s16x8*)(A + (size_t)row * 256 + ko) : zz;
#pragma unroll
        for (int ni = 0; ni < 4; ++ni) {
            s16x8 bf = *(const s16x8*)(W + (size_t)(n0 + ni * 16 + c) * 256 + ko);
            acc[ni] = __builtin_amdgcn_mfma_f32_16x16x32_bf16(af, bf, acc[ni], 0, 0, 0);
        }
    }

    __shared__ float ps1[4][16], ps2[4][16];
    float v[4][4];
#pragma unroll
    for (int r = 0; r < 4; ++r) {
        int row = m0 + 4 * qd + r;
        bool ok = (row < M);
        float s1 = 0.f, s2 = 0.f;
#pragma unroll
        for (int ni = 0; ni < 4; ++ni) {
            int col = n0 + ni * 16 + c;
            float val = acc[ni][r] + bias[col] + (ok ? R[(size_t)row * 256 + col] : 0.f);
            v[r][ni] = val;
            s1 += val; s2 += val * val;
        }
        s1 += __shfl_xor(s1, 1); s2 += __shfl_xor(s2, 1);
        s1 += __shfl_xor(s1, 2); s2 += __shfl_xor(s2, 2);
        s1 += __shfl_xor(s1, 4); s2 += __shfl_xor(s2, 4);
        s1 += __shfl_xor(s1, 8); s2 += __shfl_xor(s2, 8);
        if (c == 0) { ps1[w][4 * qd + r] = s1; ps2[w][4 * qd + r] = s2; }
    }
    __syncthreads();

    if (MODE == 0) {
#pragma unroll
        for (int r = 0; r < 4; ++r) {
            int lr = 4 * qd + r;
            int row = m0 + lr;
            if (row >= M) continue;
            float s1 = ps1[0][lr] + ps1[1][lr] + ps1[2][lr] + ps1[3][lr];
            float s2 = ps2[0][lr] + ps2[1][lr] + ps2[2][lr] + ps2[3][lr];
            float mean = s1 * (1.f / 256.f);
            float var  = s2 * (1.f / 256.f) - mean * mean;
            float rstd = rsqrtf(var + 1e-5f);
#pragma unroll
            for (int ni = 0; ni < 4; ++ni) {
                int col = n0 + ni * 16 + c;
                float y = (v[r][ni] - mean) * rstd * g[col] + bb[col];
                fout[(size_t)row * 256 + col] = y;
                bfout[(size_t)row * 256 + col] = (u16)f2bf(y);
            }
        }
    } else {
        __shared__ float ytile[2][8][256];
#pragma unroll
        for (int r = 0; r < 4; ++r) {
            int lr = 4 * qd + r;
            float s1 = ps1[0][lr] + ps1[1][lr] + ps1[2][lr] + ps1[3][lr];
            float s2 = ps2[0][lr] + ps2[1][lr] + ps2[2][lr] + ps2[3][lr];
            float mean = s1 * (1.f / 256.f);
            float var  = s2 * (1.f / 256.f) - mean * mean;
            float rstd = rsqrtf(var + 1e-5f);
#pragma unroll
            for (int ni = 0; ni < 4; ++ni) {
                int col = n0 + ni * 16 + c;
                ytile[lr & 1][lr >> 1][col] = (v[r][ni] - mean) * rstd * g[col] + bb[col];
            }
        }
        __syncthreads();
#pragma unroll
        for (int pp = tid; pp < 512; pp += 256) {
            int b = pp >> 8, col = pp & 255;
            float4 y0, y1;
            y0.x = ytile[b][0][col]; y0.y = ytile[b][1][col];
            y0.z = ytile[b][2][col]; y0.w = ytile[b][3][col];
            y1.x = ytile[b][4][col]; y1.y = ytile[b][5][col];
            y1.z = ytile[b][6][col]; y1.w = ytile[b][7][col];
            size_t o = ((size_t)(b * 256 + col)) * 1600 + (m0 >> 1);
            *(float4*)(dout + o)     = y0;
            *(float4*)(dout + o + 4) = y1;
        }
    }
}

// ===========================================================================
// K1: wconv (768) + LDS-tiled x transpose (800) + pool (200) + zero-init (3)
// ===========================================================================
__global__ __launch_bounds__(256) void k_prep(const float* __restrict__ gw,
                                              const float* __restrict__ cw,
                                              u16* __restrict__ gwb,
                                              u16* __restrict__ cwb,
                                              const float* __restrict__ x,
                                              float* __restrict__ nodes,
                                              u16* __restrict__ nodesb,
                                              float* __restrict__ gn,
                                              u16* __restrict__ gnb,
                                              float* __restrict__ sv1,
                                              u16* __restrict__ gvt,
                                              u16* __restrict__ cvt) {
    int bx = blockIdx.x;
    int tid = threadIdx.x;
    if (bx < 768) {
        int t = bx * 256 + tid;
        const float* src; u16* dst; int idx;
        if (t < 131072) { src = gw; dst = gwb; idx = t; }
        else            { src = cw; dst = cwb; idx = t - 131072; }
        float4 v = ((const float4*)src)[idx];
        ushort4 o;
        o.x = (u16)f2bf(v.x); o.y = (u16)f2bf(v.y);
        o.z = (u16)f2bf(v.z); o.w = (u16)f2bf(v.w);
        ((ushort4*)dst)[idx] = o;
    } else if (bx < 1568) {
        // LDS-tiled transpose: x[b][c][n] -> nodes[n][b][c] (f32+bf16)
        __shared__ float tile[32][33];
        int tt = bx - 768;
        int cb = tt / 100, rem = tt - cb * 100;
        int nb = rem >> 1, b = rem & 1;
        int c0 = cb * 32, n0t = nb * 32;
        int tx = tid & 31, ty = tid >> 5;
#pragma unroll
        for (int k2 = 0; k2 < 4; ++k2) {
            int cc = c0 + ty + k2 * 8;
            tile[ty + k2 * 8][tx] = x[((size_t)(b * 256 + cc)) * 1600 + n0t + tx];
        }
        __syncthreads();
#pragma unroll
        for (int k2 = 0; k2 < 4; ++k2) {
            int n = n0t + ty + k2 * 8;
            float val = tile[tx][ty + k2 * 8];
            size_t o = ((size_t)(n * 2 + b)) * 256 + c0 + tx;
            nodes[o] = val;
            nodesb[o] = (u16)f2bf(val);
        }
    } else if (bx < 1768) {
        int pt = bx - 1568;            // 0..199 = (n,b)
        int b = pt & 1, n = pt >> 1;
        int cc = tid;
        int pr = n / 10, qqc = n - pr * 10;
        const float* xp = x + ((size_t)(b * 256 + cc)) * 1600 + (pr * 4) * 40 + qqc * 4;
        float s = 0.f;
#pragma unroll
        for (int dy = 0; dy < 4; ++dy)
#pragma unroll
            for (int dx = 0; dx < 4; ++dx)
                s += xp[dy * 40 + dx];
        s *= (1.f / 16.f);
        size_t t = (size_t)pt * 256 + cc;
        gn[t] = s;
        gnb[t] = (u16)f2bf(s);
    } else if (bx == 1768) {
        sv1[tid] = 0.f;                // sv1l + sv1g contiguous 512 floats
        sv1[tid + 256] = 0.f;
    } else if (bx == 1769) {
        for (int e2 = tid; e2 < 512; e2 += 256)
            for (int n = 100; n < 128; ++n) gvt[(size_t)e2 * 128 + n] = 0;
    } else {
        for (int e2 = tid; e2 < 512; e2 += 256)
            for (int n = 100; n < 128; ++n) cvt[(size_t)e2 * 128 + n] = 0;
    }
}

// ===========================================================================
// K2: QKV GEMMs; V written transposed + colsum fused. grid (107,4,3), 64 thr.
// ===========================================================================
__global__ __launch_bounds__(64) void k_qkv(const u16* __restrict__ nodesb,
                                            const u16* __restrict__ gnb,
                                            const u16* __restrict__ W1b,
                                            const u16* __restrict__ W0b,
                                            const float* __restrict__ b1,
                                            const float* __restrict__ b0,
                                            u16* __restrict__ qbuf,
                                            u16* __restrict__ kbuf,
                                            u16* __restrict__ vtb,
                                            u16* __restrict__ gqb,
                                            u16* __restrict__ gkb,
                                            u16* __restrict__ gvt,
                                            float* __restrict__ sv1l,
                                            float* __restrict__ sv1g) {
    int lane = threadIdx.x;
    int bx = blockIdx.x, z = blockIdx.z;
    int n0 = blockIdx.y * 64;
    f32x4 acc[2][4];
    if (bx < 100) {
        int m0 = bx * 32;
        gemm_core(lane, nodesb, W1b + (size_t)z * 65536, 3200, m0, n0, acc);
        const float* bias = b1 + z * 256;
        if (z == 0)      ep_row(lane, acc, bias, qbuf, 3200, m0, n0);
        else if (z == 1) ep_row(lane, acc, bias, kbuf, 3200, m0, n0);
        else             ep_vt(lane, acc, bias, vtb, 1600, 3200, m0, n0, sv1l);
    } else {
        int m0 = (bx - 100) * 32;
        gemm_core(lane, gnb, W0b + (size_t)z * 65536, 200, m0, n0, acc);
        const float* bias = b0 + z * 256;
        if (z == 0)      ep_row(lane, acc, bias, gqb, 200, m0, n0);
        else if (z == 1) ep_row(lane, acc, bias, gkb, 200, m0, n0);
        else             ep_vt(lane, acc, bias, gvt, 128, 200, m0, n0, sv1g);
    }
}

// ===========================================================================
// K3: attention. blocks 0..799: local GAT; blocks 800..813: global GAT.
// a0 = sigmoid((q1k1-q0k0)/sqrt32); edge bias cancels; O1 = sumV1 - sum a0*V1.
// ===========================================================================
__global__ __launch_bounds__(256) void k_attn(
    const u16* __restrict__ qb, const u16* __restrict__ kb,
    const u16* __restrict__ vt, float* __restrict__ pO, float* __restrict__ pT,
    const u16* __restrict__ gqb, const u16* __restrict__ gkb,
    const u16* __restrict__ gvt, const float* __restrict__ sv1g,
    u16* __restrict__ gattb)
{
    __shared__ u16 ks[2][32][40];
    __shared__ u16 vs[2][32][40];
    __shared__ short At4[4][16][40];

    int tid = threadIdx.x;
    int w = tid >> 6, lane = tid & 63;
    int c = lane & 15, qd = lane >> 4;
    int bx = blockIdx.x;

    if (bx < 800) {
        int q4 = bx & 3;
        int hic = bx >> 2;
        int ic = hic % 25, h = hic / 25;
        int hb = h * 32;
        int i0 = ic * 64 + w * 16;
        int jb0 = q4 * 13, jbe = (jb0 + 13 < 50) ? jb0 + 13 : 50;

        const u16* qp = qb + ((size_t)(i0 + c) * 2) * 256 + hb + qd * 8;
        s16x8 qf0 = *(const s16x8*)qp;
        s16x8 qf1 = *(const s16x8*)(qp + 256);
#pragma unroll
        for (int z = 0; z < 8; ++z) qf0[z] ^= (short)0x8000;

        f32x4 o0[2] = {}, t1[2] = {};

        int srow = tid >> 2, part = tid & 3;
        int sjl = srow >> 1, sb = srow & 1;
        int vb_ = srow >> 5, vd = srow & 31;

        for (int jb = jb0; jb < jbe; ++jb) {
            int j0 = jb * 32;
            __syncthreads();
            {
                s16x8 kv = *(const s16x8*)(kb + (size_t)(j0 + sjl) * 512 + sb * 256 + hb + part * 8);
                *(s16x8*)&ks[sb][sjl][part * 8] = kv;
                s16x8 vv = *(const s16x8*)(vt + (size_t)(vb_ * 256 + hb + vd) * 1600 + j0 + part * 8);
                *(s16x8*)&vs[vb_][vd][part * 8] = vv;
            }
            __syncthreads();

            s16x8 kf00 = *(const s16x8*)&ks[0][c][qd * 8];
            s16x8 kf10 = *(const s16x8*)&ks[1][c][qd * 8];
            s16x8 kf01 = *(const s16x8*)&ks[0][16 + c][qd * 8];
            s16x8 kf11 = *(const s16x8*)&ks[1][16 + c][qd * 8];

            f32x4 z4 = {};
            f32x4 sd0 = __builtin_amdgcn_mfma_f32_16x16x32_bf16(qf0, kf00, z4, 0, 0, 0);
            sd0       = __builtin_amdgcn_mfma_f32_16x16x32_bf16(qf1, kf10, sd0, 0, 0, 0);
            f32x4 sd1 = __builtin_amdgcn_mfma_f32_16x16x32_bf16(qf0, kf01, z4, 0, 0, 0);
            sd1       = __builtin_amdgcn_mfma_f32_16x16x32_bf16(qf1, kf11, sd1, 0, 0, 0);
#pragma unroll
            for (int r = 0; r < 4; ++r) {
                float e0v = __expf(sd0[r] * 0.17677669529663687f);
                At4[w][4 * qd + r][c]      = f2bf(__builtin_amdgcn_rcpf(1.f + e0v));
                float e1v = __expf(sd1[r] * 0.17677669529663687f);
                At4[w][4 * qd + r][16 + c] = f2bf(__builtin_amdgcn_rcpf(1.f + e1v));
            }
            asm volatile("s_waitcnt lgkmcnt(0)" ::: "memory");
            s16x8 af = *(const s16x8*)&At4[w][c][qd * 8];

            s16x8 vf00 = *(const s16x8*)&vs[0][c][qd * 8];
            s16x8 vf01 = *(const s16x8*)&vs[0][16 + c][qd * 8];
            s16x8 vf10 = *(const s16x8*)&vs[1][c][qd * 8];
            s16x8 vf11 = *(const s16x8*)&vs[1][16 + c][qd * 8];

            o0[0] = __builtin_amdgcn_mfma_f32_16x16x32_bf16(af, vf00, o0[0], 0, 0, 0);
            o0[1] = __builtin_amdgcn_mfma_f32_16x16x32_bf16(af, vf01, o0[1], 0, 0, 0);
            t1[0] = __builtin_amdgcn_mfma_f32_16x16x32_bf16(af, vf10, t1[0], 0, 0, 0);
            t1[1] = __builtin_amdgcn_mfma_f32_16x16x32_bf16(af, vf11, t1[1], 0, 0, 0);
        }

        size_t base = (size_t)q4 * 409600;
#pragma unroll
        for (int dh = 0; dh < 2; ++dh)
#pragma unroll
            for (int r = 0; r < 4; ++r) {
                size_t idx = base + (size_t)(i0 + 4 * qd + r) * 256 + hb + dh * 16 + c;
                pO[idx] = o0[dh][r];
                pT[idx] = t1[dh][r];
            }
    } else {
        int idx = (bx - 800) * 4 + w;      // 0..55 exact
        int h = idx / 7, it = idx % 7;
        int i0 = it * 16;
        int hb = h * 32;

        s16x8 qf0 = {}, qf1 = {};
        int i = i0 + c;
        if (i < NGLO) {
            const u16* qp = gqb + ((size_t)i * 2) * 256 + hb + qd * 8;
            qf0 = *(const s16x8*)qp;
            qf1 = *(const s16x8*)(qp + 256);
        }
#pragma unroll
        for (int z = 0; z < 8; ++z) qf0[z] ^= (short)0x8000;

        f32x4 o0[2] = {}, t1[2] = {};

        for (int j0 = 0; j0 < NGLO; j0 += 32) {
            s16x8 kf[2][2], vf[2][2];
#pragma unroll
            for (int b = 0; b < 2; ++b)
#pragma unroll
                for (int js = 0; js < 2; ++js) {
                    int j = j0 + js * 16 + c;
                    s16x8 kv = {};
                    if (j < NGLO) kv = *(const s16x8*)(gkb + ((size_t)j * 2 + b) * 256 + hb + qd * 8);
                    kf[b][js] = kv;
                }
#pragma unroll
            for (int b = 0; b < 2; ++b)
#pragma unroll
                for (int dh = 0; dh < 2; ++dh)
                    vf[b][dh] = *(const s16x8*)(gvt + (size_t)(b * 256 + hb + dh * 16 + c) * 128
                                                + j0 + qd * 8);

            f32x4 z4 = {};
            f32x4 sd0 = __builtin_amdgcn_mfma_f32_16x16x32_bf16(qf0, kf[0][0], z4, 0, 0, 0);
            sd0       = __builtin_amdgcn_mfma_f32_16x16x32_bf16(qf1, kf[1][0], sd0, 0, 0, 0);
            f32x4 sd1 = __builtin_amdgcn_mfma_f32_16x16x32_bf16(qf0, kf[0][1], z4, 0, 0, 0);
            sd1       = __builtin_amdgcn_mfma_f32_16x16x32_bf16(qf1, kf[1][1], sd1, 0, 0, 0);
#pragma unroll
            for (int r = 0; r < 4; ++r) {
                float e0v = __expf(sd0[r] * 0.17677669529663687f);
                At4[w][4 * qd + r][c]      = f2bf(__builtin_amdgcn_rcpf(1.f + e0v));
                float e1v = __expf(sd1[r] * 0.17677669529663687f);
                At4[w][4 * qd + r][16 + c] = f2bf(__builtin_amdgcn_rcpf(1.f + e1v));
            }
            asm volatile("s_waitcnt lgkmcnt(0)" ::: "memory");
            s16x8 af = *(const s16x8*)&At4[w][c][qd * 8];
            o0[0] = __builtin_amdgcn_mfma_f32_16x16x32_bf16(af, vf[0][0], o0[0], 0, 0, 0);
            o0[1] = __builtin_amdgcn_mfma_f32_16x16x32_bf16(af, vf[0][1], o0[1], 0, 0, 0);
            t1[0] = __builtin_amdgcn_mfma_f32_16x16x32_bf16(af, vf[1][0], t1[0], 0, 0, 0);
            t1[1] = __builtin_amdgcn_mfma_f32_16x16x32_bf16(af, vf[1][1], t1[1], 0, 0, 0);
        }

#pragma unroll
        for (int dh = 0; dh < 2; ++dh) {
            float sv = sv1g[hb + dh * 16 + c];
#pragma unroll
            for (int r = 0; r < 4; ++r) {
                int ii = i0 + 4 * qd + r;
                if (ii < NGLO) {
                    size_t o = ((size_t)ii * 2) * 256 + hb + dh * 16 + c;
                    gattb[o]       = (u16)f2bf(o0[dh][r]);
                    gattb[o + 256] = (u16)f2bf(sv - t1[dh][r]);
                }
            }
        }
    }
}

// ===========================================================================
// K4: combine (bx<400) + global proj+LN fused (bx in [400,413)).
// ===========================================================================
__global__ __launch_bounds__(256) void k_combine_gproj(
    const float* __restrict__ pO, const float* __restrict__ pT,
    const float* __restrict__ sv1l, u16* __restrict__ attb,
    const u16* __restrict__ gattb, const u16* __restrict__ W0p,
    const float* __restrict__ b0p, const float* __restrict__ gn,
    const float* __restrict__ ln_g, const float* __restrict__ ln_b,
    float* __restrict__ gout, u16* __restrict__ goutb)
{
    int bx = blockIdx.x;
    if (bx < 400) {
        int t4 = (bx * 256 + threadIdx.x) * 4;
        int e = t4 & 255;
        int i = t4 >> 8;
        float4 o  = *(const float4*)(pO + t4);
        float4 tt = *(const float4*)(pT + t4);
#pragma unroll
        for (int q = 1; q < 4; ++q) {
            float4 a = *(const float4*)(pO + t4 + q * 409600);
            float4 b = *(const float4*)(pT + t4 + q * 409600);
            o.x += a.x; o.y += a.y; o.z += a.z; o.w += a.w;
            tt.x += b.x; tt.y += b.y; tt.z += b.z; tt.w += b.w;
        }
        float4 sv = *(const float4*)(sv1l + e);
        ushort4 w0, w1;
        w0.x = (u16)f2bf(o.x); w0.y = (u16)f2bf(o.y);
        w0.z = (u16)f2bf(o.z); w0.w = (u16)f2bf(o.w);
        w1.x = (u16)f2bf(sv.x - tt.x); w1.y = (u16)f2bf(sv.y - tt.y);
        w1.z = (u16)f2bf(sv.z - tt.z); w1.w = (u16)f2bf(sv.w - tt.w);
        *(ushort4*)(attb + (size_t)i * 512 + e)       = w0;
        *(ushort4*)(attb + (size_t)i * 512 + 256 + e) = w1;
    } else {
        gemmln_block<0>(threadIdx.x, gattb, W0p, b0p, gn, ln_g, ln_b,
                        gout, goutb, (float*)0, 200, (bx - 400) * 16);
    }
}

// ===========================================================================
// K5: local proj+LN fused (bx<200) + ck/cv GEMM (bx>=200, cv transposed).
// ===========================================================================
__global__ __launch_bounds__(256) void k_lproj_ckcv(
    const u16* __restrict__ attb, const u16* __restrict__ W1p,
    const float* __restrict__ b1p, const float* __restrict__ nodes,
    const float* __restrict__ ln_g1, const float* __restrict__ ln_b1,
    float* __restrict__ lout, u16* __restrict__ loutb,
    const u16* __restrict__ goutb, const u16* __restrict__ wckv,
    const float* __restrict__ bckv, u16* __restrict__ ckb,
    u16* __restrict__ cvt)
{
    int bx = blockIdx.x;
    if (bx < 200) {
        gemmln_block<0>(threadIdx.x, attb, W1p, b1p, nodes, ln_g1, ln_b1,
                        lout, loutb, (float*)0, 3200, bx * 16);
    } else {
        int w = threadIdx.x >> 6, lane = threadIdx.x & 63;
        int idx = (bx - 200) * 4 + w;                  // 0..55
        if (idx < 56) {
            int z = idx / 28, rem = idx % 28;
            int m0 = (rem >> 2) * 32, n0 = (rem & 3) * 64;
            f32x4 acc[2][4];
            gemm_core(lane, goutb, wckv + (size_t)z * 65536, 200, m0, n0, acc);
            const float* bias = bckv + z * 256;
            if (z == 0) ep_row(lane, acc, bias, ckb, 200, m0, n0);
            else        ep_vt(lane, acc, bias, cvt, 128, 200, m0, n0, (float*)0);
        }
    }
}

// ===========================================================================
// K6: cross attention with INLINE cq GEMM. 400 blocks x 4 waves = 1600 tasks.
// Each wave: compute q tile 16x32 from loutb (16 MFMAs) -> LDS layout fix ->
// softmax over 100 pooled keys -> PV.
// ===========================================================================
__global__ __launch_bounds__(256) void k_cross(
    const u16* __restrict__ loutb, const u16* __restrict__ wcq,
    const float* __restrict__ bcq, const u16* __restrict__ kb,
    const u16* __restrict__ vt, u16* __restrict__ out)
{
    __shared__ short At[4][16][136];
    __shared__ short Aq[4][16][40];
    int w = threadIdx.x >> 6, lane = threadIdx.x & 63;
    int c  = lane & 15;
    int qd = lane >> 4;
    int idx = blockIdx.x * 4 + w;
    int it = idx % 100;
    int hb2 = idx / 100;
    int h = hb2 >> 1, b = hb2 & 1;
    int i0 = it * 16;
    int hb = h * 32;

    for (int z = lane; z < 16 * 24; z += 64)
        At[w][z / 24][112 + (z % 24)] = 0;

    // ---- inline cq: q[i0..+16][hb..+32] = lout @ Wq^T + b ----
    f32x4 qacc[2] = {};
#pragma unroll 2
    for (int kc = 0; kc < 8; ++kc) {
        int ko = kc * 32 + qd * 8;
        s16x8 af = *(const s16x8*)(loutb + ((size_t)(i0 + c) * 2 + b) * 256 + ko);
#pragma unroll
        for (int ni = 0; ni < 2; ++ni) {
            s16x8 bf = *(const s16x8*)(wcq + (size_t)(hb + ni * 16 + c) * 256 + ko);
            qacc[ni] = __builtin_amdgcn_mfma_f32_16x16x32_bf16(af, bf, qacc[ni], 0, 0, 0);
        }
    }
#pragma unroll
    for (int ni = 0; ni < 2; ++ni)
#pragma unroll
        for (int r = 0; r < 4; ++r)
            Aq[w][4 * qd + r][ni * 16 + c] = f2bf(qacc[ni][r] + bcq[hb + ni * 16 + c]);
    asm volatile("s_waitcnt lgkmcnt(0)" ::: "memory");
    s16x8 qf = *(const s16x8*)&Aq[w][c][qd * 8];

    // ---- S = Q K^T over 7 key tiles ----
    f32x4 s[7];
#pragma unroll
    for (int jt = 0; jt < 7; ++jt) {
        int j = jt * 16 + c;
        s16x8 kf = {};
        if (j < NGLO) kf = *(const s16x8*)(kb + ((size_t)j * 2 + b) * 256 + hb + qd * 8);
        f32x4 z4 = {};
        s[jt] = __builtin_amdgcn_mfma_f32_16x16x32_bf16(qf, kf, z4, 0, 0, 0);
    }
    if (c >= 4) {
#pragma unroll
        for (int r = 0; r < 4; ++r) s[6][r] = -1e30f;
    }
#pragma unroll
    for (int jt = 0; jt < 7; ++jt)
#pragma unroll
        for (int r = 0; r < 4; ++r) s[jt][r] *= 0.17677669529663687f;

    float l[4];
#pragma unroll
    for (int r = 0; r < 4; ++r) {
        float mm = s[0][r];
#pragma unroll
        for (int jt = 1; jt < 7; ++jt) mm = fmaxf(mm, s[jt][r]);
        mm = fmaxf(mm, __shfl_xor(mm, 1));
        mm = fmaxf(mm, __shfl_xor(mm, 2));
        mm = fmaxf(mm, __shfl_xor(mm, 4));
        mm = fmaxf(mm, __shfl_xor(mm, 8));
        float ll = 0.f;
#pragma unroll
        for (int jt = 0; jt < 7; ++jt) {
            float pv = __expf(s[jt][r] - mm);
            s[jt][r] = pv;
            ll += pv;
        }
        ll += __shfl_xor(ll, 1);
        ll += __shfl_xor(ll, 2);
        ll += __shfl_xor(ll, 4);
        ll += __shfl_xor(ll, 8);
        l[r] = ll;
    }
#pragma unroll
    for (int jt = 0; jt < 7; ++jt)
#pragma unroll
        for (int r = 0; r < 4; ++r)
            At[w][4 * qd + r][jt * 16 + c] = f2bf(s[jt][r]);
    asm volatile("s_waitcnt lgkmcnt(0)" ::: "memory");

    f32x4 o[2] = {};
#pragma unroll
    for (int kc = 0; kc < 4; ++kc) {
        s16x8 af = *(const s16x8*)&At[w][c][kc * 32 + qd * 8];
#pragma unroll
        for (int dh = 0; dh < 2; ++dh) {
            s16x8 vf = *(const s16x8*)(vt + (size_t)(b * 256 + hb + dh * 16 + c) * 128
                                       + kc * 32 + qd * 8);
            o[dh] = __builtin_amdgcn_mfma_f32_16x16x32_bf16(af, vf, o[dh], 0, 0, 0);
        }
    }
#pragma unroll
    for (int dh = 0; dh < 2; ++dh)
#pragma unroll
        for (int r = 0; r < 4; ++r) {
            int ii = i0 + 4 * qd + r;
            out[((size_t)ii * 2 + b) * 256 + hb + dh * 16 + c] = (u16)f2bf(o[dh][r] / l[r]);
        }
}

// ===========================================================================
// K7: final cproj + LN fused, writes BCHW output. 200 blocks.
// ===========================================================================
__global__ __launch_bounds__(256) void k_cproj(
    const u16* __restrict__ cattb, const u16* __restrict__ wcp,
    const float* __restrict__ bcp, const float* __restrict__ lout,
    const float* __restrict__ ln_g2, const float* __restrict__ ln_b2,
    float* __restrict__ dout)
{
    gemmln_block<1>(threadIdx.x, cattb, wcp, bcp, lout, ln_g2, ln_b2,
                    (float*)0, (u16*)0, dout, 3200, blockIdx.x * 16);
}

// ===========================================================================
extern "C" void kernel_launch(void* const* d_in, const int* in_sizes, int n_in,
                              void* d_out, int out_size, void* d_ws, size_t ws_size,
                              hipStream_t stream) {
    const float* x        = (const float*)d_in[0];
    const float* gat_W    = (const float*)d_in[1];
    const float* gat_b    = (const float*)d_in[2];
    // d_in[3] = gat_rel: cancels in the batch-axis softmax -> unused
    const float* cross_W  = (const float*)d_in[4];
    const float* cross_b  = (const float*)d_in[5];
    const float* ln_g     = (const float*)d_in[6];
    const float* ln_b     = (const float*)d_in[7];
    float* out = (float*)d_out;

    float* ws    = (float*)d_ws;
    float* nodes = ws;                      // [3200][256] f32
    float* gn    = nodes + 819200;          // [200][256]
    float* gout  = gn + 51200;
    float* lout  = gout + 51200;            // [3200][256]
    float* sv1l  = lout + 819200;           // [256]; sv1g contiguous
    float* sv1g  = sv1l + 256;
    float* pO    = sv1g + 256;              // [4][1600][256]
    float* pT    = pO + 1638400;

    u16* ub = (u16*)(pT + 1638400);
    u16* wgatb  = ub;            ub += 524288;
    u16* wcrsb  = ub;            ub += 262144;
    u16* nodesb = ub;            ub += 819200;
    u16* gnb    = ub;            ub += 51200;
    u16* qbuf   = ub;            ub += 819200;
    u16* kbuf   = ub;            ub += 819200;   // consumed by K3 -> cattb alias
    u16* vtb    = ub;            ub += 819200;
    u16* gqb    = ub;            ub += 51200;
    u16* gkb    = ub;            ub += 51200;
    u16* gvt    = ub;            ub += 65536;
    u16* gattb  = ub;            ub += 51200;
    u16* goutb  = ub;            ub += 51200;
    u16* attb   = ub;            ub += 819200;
    u16* loutb  = ub;            ub += 819200;
    u16* ckb    = ub;            ub += 51200;
    u16* cvt    = ub;            ub += 65536;
    u16* cattb  = kbuf;                          // reuse

    const u16* W0b = wgatb;
    const u16* W1b = wgatb + 4 * 65536;
    const float* b0 = gat_b;
    const float* b1 = gat_b + 4 * 256;

    k_prep<<<1771, 256, 0, stream>>>(gat_W, cross_W, wgatb, wcrsb,
                                     x, nodes, nodesb, gn, gnb, sv1l, gvt, cvt);
    k_qkv<<<dim3(107, 4, 3), 64, 0, stream>>>(nodesb, gnb, W1b, W0b, b1, b0,
                                              qbuf, kbuf, vtb, gqb, gkb, gvt,
                                              sv1l, sv1g);
    k_attn<<<814, 256, 0, stream>>>(qbuf, kbuf, vtb, pO, pT,
                                    gqb, gkb, gvt, sv1g, gattb);
    k_combine_gproj<<<413, 256, 0, stream>>>(pO, pT, sv1l, attb,
                                             gattb, W0b + 3 * 65536, b0 + 768, gn,
                                             ln_g, ln_b, gout, goutb);
    k_lproj_ckcv<<<214, 256, 0, stream>>>(attb, W1b + 3 * 65536, b1 + 768, nodes,
                                          ln_g + 256, ln_b + 256, lout, loutb,
                                          goutb, wcrsb + 65536, cross_b + 256,
                                          ckb, cvt);
    k_cross<<<400, 256, 0, stream>>>(loutb, wcrsb, cross_b, ckb, cvt, cattb);
    k_cproj<<<200, 256, 0, stream>>>(cattb, wcrsb + 3 * 65536, cross_b + 768, lout,
                                     ln_g + 512, ln_b + 512, out);
}